// Round 2
// baseline (227.366 us; speedup 1.0000x reference)
//
#include <hip/hip_runtime.h>
#include <hip/hip_bf16.h>

#define NF    32
#define ED    128
#define NBATCH 2048
#define NPAIRS 496
#define BM    128
#define MBLKS (NBATCH / BM)          // 16
#define NWG   (NPAIRS * MBLKS)       // 7936

typedef __attribute__((ext_vector_type(8))) short  short8;   // 8 bf16 = 4 VGPR (MFMA A/B frag)
typedef __attribute__((ext_vector_type(4))) float  f32x4;    // MFMA C/D frag

__device__ __forceinline__ unsigned short f2bf(float x) {
    union { float f; unsigned int u; } v; v.f = x;
    unsigned int r = v.u + 0x7FFFu + ((v.u >> 16) & 1u);   // round-to-nearest-even
    return (unsigned short)(r >> 16);
}

// LDS byte layout (both tiles): row-major 128 rows x 256 B, swizzled:
//   byte(row, col_byte) = row*256 + (col_byte ^ ((row & 15) << 4))
// -> fragment reads (16 lanes, 16 consecutive rows, same col slot) hit 16
//    distinct 16B slots => conflict-free ds_read_b128.

__global__ __launch_bounds__(256, 2)
void bilinear_mfma_kernel(const float* __restrict__ femb,
                          const float* __restrict__ W,
                          float* __restrict__ out)
{
    __shared__ unsigned char ldsA[128 * 256];  // A tile: [m][d] bf16, swizzled
    __shared__ unsigned char ldsB[128 * 256];  // W tile: [e][d] bf16, swizzled (W is ALREADY [p][e][d])

    // XCD-aware chunk swizzle (NWG divisible by 8): the 16 M-blocks of one
    // pair land on one XCD -> W[p] (64 KB bf16-source = 64KB fp32 reads x16) is L2-hot.
    int bid = blockIdx.x;
    int wg  = (bid & 7) * (NWG / 8) + (bid >> 3);
    int p   = wg >> 4;          // pair index 0..495
    int mb  = wg & 15;          // M-block 0..15

    // pair -> (i, j) per lexicographic combinations(range(32), 2)
    int fi = 0, rem = p;
    while (rem >= NF - 1 - fi) { rem -= NF - 1 - fi; ++fi; }
    int fj = fi + 1 + rem;

    const int t    = threadIdx.x;
    const int lane = t & 63;
    const int wave = t >> 6;
    const int b0   = mb * BM;

    // ---- Stage A: femb[b0+r][fi][d] -> bf16 LDS, row-major [r][d] ----
    #pragma unroll
    for (int it = 0; it < 8; ++it) {
        int idx8 = it * 2048 + t * 8;
        int r = idx8 >> 7;            // 0..127
        int d = idx8 & 127;           // multiple of 8
        const float* s = femb + ((size_t)(b0 + r) * NF + fi) * ED + d;
        float4 lo = *reinterpret_cast<const float4*>(s);
        float4 hi = *reinterpret_cast<const float4*>(s + 4);
        short8 pk;
        pk[0] = (short)f2bf(lo.x); pk[1] = (short)f2bf(lo.y);
        pk[2] = (short)f2bf(lo.z); pk[3] = (short)f2bf(lo.w);
        pk[4] = (short)f2bf(hi.x); pk[5] = (short)f2bf(hi.y);
        pk[6] = (short)f2bf(hi.z); pk[7] = (short)f2bf(hi.w);
        int byte = r * 256 + ((d * 2) ^ ((r & 15) << 4));
        *reinterpret_cast<short8*>(ldsA + byte) = pk;
    }

    // ---- Stage B: W[p][e][d] -> bf16 LDS, row-major [e][d] (no transpose!) ----
    {
        const float* wp = W + (size_t)p * (ED * ED);
        #pragma unroll
        for (int it = 0; it < 8; ++it) {
            int idx8 = it * 2048 + t * 8;
            int e = idx8 >> 7;        // 0..127
            int d = idx8 & 127;       // multiple of 8
            const float* s = wp + (size_t)e * ED + d;
            float4 lo = *reinterpret_cast<const float4*>(s);
            float4 hi = *reinterpret_cast<const float4*>(s + 4);
            short8 pk;
            pk[0] = (short)f2bf(lo.x); pk[1] = (short)f2bf(lo.y);
            pk[2] = (short)f2bf(lo.z); pk[3] = (short)f2bf(lo.w);
            pk[4] = (short)f2bf(hi.x); pk[5] = (short)f2bf(hi.y);
            pk[6] = (short)f2bf(hi.z); pk[7] = (short)f2bf(hi.w);
            int byte = e * 256 + ((d * 2) ^ ((e & 15) << 4));
            *reinterpret_cast<short8*>(ldsB + byte) = pk;
        }
    }

    __syncthreads();

    // ---- Compute: each wave owns a 64x64 quadrant ----
    const int wr  = wave >> 1;      // 0..1
    const int wc  = wave & 1;       // 0..1
    const int lhi = lane >> 4;      // 0..3
    const int llo = lane & 15;      // 0..15

    f32x4 acc[4][4] = {};

    #pragma unroll
    for (int kk = 0; kk < 4; ++kk) {
        const int db = kk * 64 + lhi * 16;   // k-offset in bytes, 16B aligned
        short8 a[4], b[4];
        #pragma unroll
        for (int mi = 0; mi < 4; ++mi) {
            int r = wr * 64 + mi * 16 + llo;           // r & 15 == llo
            a[mi] = *reinterpret_cast<const short8*>(ldsA + r * 256 + (db ^ (llo << 4)));
        }
        #pragma unroll
        for (int ni = 0; ni < 4; ++ni) {
            int e = wc * 64 + ni * 16 + llo;           // e & 15 == llo
            b[ni] = *reinterpret_cast<const short8*>(ldsB + e * 256 + (db ^ (llo << 4)));
        }
        #pragma unroll
        for (int mi = 0; mi < 4; ++mi)
            #pragma unroll
            for (int ni = 0; ni < 4; ++ni)
                acc[mi][ni] = __builtin_amdgcn_mfma_f32_16x16x32_bf16(a[mi], b[ni], acc[mi][ni], 0, 0, 0);
    }

    // ---- Epilogue: out[b][p][e] = acc * femb[b][fj][e] (fp32) ----
    // D frag: row_local = lhi*4 + q, col_local = llo  (verified m89/m91 mapping)
    #pragma unroll
    for (int mi = 0; mi < 4; ++mi) {
        #pragma unroll
        for (int q = 0; q < 4; ++q) {
            int b = b0 + wr * 64 + mi * 16 + lhi * 4 + q;
            const float* vj = femb + ((size_t)b * NF + fj) * ED;
            float* op = out + ((size_t)b * NPAIRS + p) * ED;
            #pragma unroll
            for (int ni = 0; ni < 4; ++ni) {
                int e = wc * 64 + ni * 16 + llo;
                op[e] = acc[mi][ni][q] * vj[e];
            }
        }
    }
}

extern "C" void kernel_launch(void* const* d_in, const int* in_sizes, int n_in,
                              void* d_out, int out_size, void* d_ws, size_t ws_size,
                              hipStream_t stream) {
    (void)in_sizes; (void)n_in; (void)out_size; (void)d_ws; (void)ws_size;
    const float* femb = (const float*)d_in[0];
    const float* W    = (const float*)d_in[1];
    float* out        = (float*)d_out;
    hipLaunchKernelGGL(bilinear_mfma_kernel, dim3(NWG), dim3(256), 0, stream,
                       femb, W, out);
}